// Round 6
// baseline (2096.763 us; speedup 1.0000x reference)
//
#include <hip/hip_runtime.h>
#include <hip/hip_bf16.h>

// Problem constants
#define BB 32    // batch
#define TT 128   // T_E == T_D
#define HH 256   // hidden

__device__ __forceinline__ float rcp_f(float x) { return __builtin_amdgcn_rcpf(x); }
__device__ __forceinline__ float sigmoid_f(float x) {
    return rcp_f(1.f + __expf(-x));  // ~1e-7 rel err vs 7e-3 threshold
}
__device__ __forceinline__ float tanh_f(float x) {
    float e = __expf(2.f * x);
    return 1.f - 2.f * rcp_f(e + 1.f);
}

// ---------------------------------------------------------------------------
// LSTM — R21: single block per batch. NO cross-block exchange (the ~2700cy
// mbox RTT/detect of R12..R20 is deleted). Whh streamed from L2 every step
// (1 MB/step/block; 4 blocks/XCD share one L2-resident copy).
// grid = 32 (block b = batch); block = 1024 = 16 waves.
// Dot layout: wave w owns rows w*64..+64 (row = gate*256+unit). Lane =
// rli*8+kli: 8 rows x 8 k-chunks per pass, 8 passes. Weight loads coalesced
// (8 kli-lanes x 16B contiguous per row); h in 8 float4 regs/lane, loaded
// once per step via LDS broadcast; 3-shfl reduce; lane kli==0 writes g_lds.
// Act: threads 0..255 (unit u): gates from g_lds + bias + Wih*x, c/h in
// registers, h -> h_lds + hs[] global (for the separate proj kernel).
// Measured ledger:
//   R15 4-block row-split: 484us (chain = RTT 2700 + dot/act 1800)
//   R16 lgkm-barrier NULL | R17 gate-colocate 706 | R18 pk_fma 589
//   R19 XCD-coloring NULL | R20 partial-sum exchange 658 (WRITE 419MB)
// Pre-commit: lstm >= 484us => restore R15, declare practical floor.
// ---------------------------------------------------------------------------
__global__ __launch_bounds__(1024, 4) void lstm_kernel(
    const float* __restrict__ seq,     // [B][128]
    const int* __restrict__ seq_m,     // [B]
    const float* __restrict__ target,  // [B][128]
    const float* __restrict__ Wih_e,   // [1024]
    const float* __restrict__ Whh_e,   // [1024][256]
    const float* __restrict__ bih_e, const float* __restrict__ bhh_e,
    const float* __restrict__ Wih_d, const float* __restrict__ Whh_d,
    const float* __restrict__ bih_d, const float* __restrict__ bhh_d,
    float* __restrict__ hs)  // [B][2T][H] h history (proj kernel input)
{
    const int b = blockIdx.x;
    const int tid = threadIdx.x;
    const int w = tid >> 6;          // wave 0..15
    const int lane = tid & 63;
    const int rli = lane >> 3;       // row-lane 0..7
    const int kli = lane & 7;        // k-lane 0..7
    const int rbase = w * 64 + rli;  // + p*8
    const int last = seq_m[b] - 1;

    __shared__ float h_lds[HH];
    __shared__ float g_lds[4 * HH];
    __shared__ float x_lds[2 * TT];

    for (int i = tid; i < 2 * TT; i += 1024)
        x_lds[i] = (i < TT) ? seq[b * TT + i] : target[b * TT + (i - TT)];

    // act-role constants (threads 0..255, unit u = tid)
    float bact[4], wact[4];
    auto loadact = [&](const float* Wih, const float* bih, const float* bhh) {
        if (tid < HH) {
#pragma unroll
            for (int k = 0; k < 4; ++k) {
                const int r = k * HH + tid;
                bact[k] = bih[r] + bhh[r];
                wact[k] = Wih[r];
            }
        }
    };
    loadact(Wih_e, bih_e, bhh_e);

    if (tid < 64) ((float4*)h_lds)[tid] = make_float4(0.f, 0.f, 0.f, 0.f);
    __syncthreads();

    float c = 0.f, csv = 0.f, hsv = 0.f;

    for (int t = 0; t < 2 * TT; ++t) {
        const float* Wc = (t < TT) ? Whh_e : Whh_d;

        // h chunk regs: lane kli covers float4 indices {kli+8i}, fixed all step.
        // LDS broadcast (8 kli-lanes read 8 distinct float4 = conflict-free).
        float4 hreg[8];
        const float4* h4 = (const float4*)h_lds;
#pragma unroll
        for (int i = 0; i < 8; ++i) hreg[i] = h4[kli + 8 * i];

        // 8 passes x 8 rows: coalesced weight stream from L2
#pragma unroll
        for (int p = 0; p < 8; ++p) {
            const int r = rbase + p * 8;
            const float4* wr = ((const float4*)(Wc + r * HH)) + kli;
            float a = 0.f;
#pragma unroll
            for (int i = 0; i < 8; ++i) {
                float4 wv = wr[8 * i];  // imm-offset ladder, 128B stride
                a = fmaf(wv.x, hreg[i].x, a);
                a = fmaf(wv.y, hreg[i].y, a);
                a = fmaf(wv.z, hreg[i].z, a);
                a = fmaf(wv.w, hreg[i].w, a);
            }
            a += __shfl_xor(a, 1);
            a += __shfl_xor(a, 2);
            a += __shfl_xor(a, 4);  // sum the 8 kli partials
            if (kli == 0) g_lds[r] = a;
        }
        __syncthreads();  // (A) gates complete; h_lds consumed (hreg loaded)

        // ---- act (threads 0..255): unit u = tid ----
        if (tid < HH) {
            const float x = x_lds[t];
            float gi = g_lds[tid] + bact[0] + x * wact[0];
            float gf = g_lds[HH + tid] + bact[1] + x * wact[1];
            float gg = g_lds[2 * HH + tid] + bact[2] + x * wact[2];
            float go = g_lds[3 * HH + tid] + bact[3] + x * wact[3];
            float si = sigmoid_f(gi);
            float sf = sigmoid_f(gf);
            float tg = tanh_f(gg);
            float so = sigmoid_f(go);
            c = sf * c + si * tg;
            float h = so * tanh_f(c);
            if (t < TT && t == last) { csv = c; hsv = h; }
            hs[((size_t)b * 2 * TT + t) * HH + tid] = h;  // off-chain history
            h_lds[tid] = (t == TT - 1) ? hsv : h;         // decoder h0 = e_hs
        }
        __syncthreads();  // (B) h_lds ready for next dot

        if (t == TT - 1) {  // encoder -> decoder transition (all local)
            loadact(Wih_d, bih_d, bhh_d);
            c = csv;
        }
    }
}

// ---------------------------------------------------------------------------
// Projections: e2 = hs_e @ We^T + be ; d2 = hs_d @ Wd^T + bd.
// grid = 256 = b(32) x 8 t-tiles(32 rows over 2T); block = 256 (thread = col).
// Per thread: acc[32] rows, k-loop with W row from L2 and h via LDS broadcast.
// ~1.07 GFLOP total => ~10us.
// ---------------------------------------------------------------------------
__global__ __launch_bounds__(256) void proj_kernel(
    const float* __restrict__ hs, const float* __restrict__ We,
    const float* __restrict__ be, const float* __restrict__ Wd,
    const float* __restrict__ bd, float* __restrict__ e2,
    float* __restrict__ d2) {
    const int blk = blockIdx.x;
    const int b = blk >> 3;
    const int t0 = (blk & 7) * 32;  // 0..224 over 2T
    const int tid = threadIdx.x;    // output col

    __shared__ float hl[32][HH];
    for (int idx = tid; idx < 32 * 64; idx += 256) {
        int r = idx >> 6, q = idx & 63;
        ((float4*)hl[r])[q] =
            ((const float4*)(hs + ((size_t)b * 2 * TT + t0 + r) * HH))[q];
    }
    __syncthreads();

    const bool enc = t0 < TT;
    const float* W = enc ? We : Wd;
    const float bias = enc ? be[tid] : bd[tid];

    float acc[32];
#pragma unroll
    for (int r = 0; r < 32; ++r) acc[r] = 0.f;

    const float4* w4 = (const float4*)(W + tid * HH);
    for (int k4 = 0; k4 < 64; ++k4) {
        float4 wv = w4[k4];
#pragma unroll
        for (int r = 0; r < 32; ++r) {
            float4 hv = ((const float4*)hl[r])[k4];  // broadcast read
            acc[r] = fmaf(wv.x, hv.x, acc[r]);
            acc[r] = fmaf(wv.y, hv.y, acc[r]);
            acc[r] = fmaf(wv.z, hv.z, acc[r]);
            acc[r] = fmaf(wv.w, hv.w, acc[r]);
        }
    }

    float* out = enc ? (e2 + ((size_t)b * TT + t0) * HH)
                     : (d2 + ((size_t)b * TT + (t0 - TT)) * HH);
#pragma unroll
    for (int r = 0; r < 32; ++r) out[r * HH + tid] = acc[r] + bias;
}

// ---------------------------------------------------------------------------
// Attention scores: p = tanh(e2_j + d2_i) . v  for a 32x32 (i,j) tile.
// grid = 512 = b(32) x it(4) x jt(4); block = 256; 4x i-register-blocked.
// (unchanged, measured ~75us)
// ---------------------------------------------------------------------------
#define EPAD 260  // float4-aligned LDS row stride
__global__ __launch_bounds__(256) void attn_p_kernel(
    const float* __restrict__ e2, const float* __restrict__ d2,
    const float* __restrict__ vv, float* __restrict__ p_ws) {
    __shared__ float e2c[32][EPAD];
    __shared__ float d2t[32][EPAD];
    __shared__ float v_lds[HH];

    const int blk = blockIdx.x;
    const int b = blk >> 4;
    const int i0 = ((blk >> 2) & 3) * 32;
    const int j0 = (blk & 3) * 32;
    const int tid = threadIdx.x;
    const int jl = tid & 31, ig = tid >> 5;

    if (tid < 64) *(float4*)&v_lds[tid * 4] = ((const float4*)vv)[tid];
    for (int idx = tid; idx < 32 * 64; idx += 256) {
        int r = idx >> 6, q = idx & 63;
        *(float4*)&d2t[r][q * 4] = ((const float4*)(d2 + (b * TT + i0 + r) * HH))[q];
        *(float4*)&e2c[r][q * 4] = ((const float4*)(e2 + (b * TT + j0 + r) * HH))[q];
    }
    __syncthreads();

    float a0 = 0.f, a1 = 0.f, a2 = 0.f, a3 = 0.f;
    for (int h = 0; h < HH; h += 4) {
        float4 ev = *(const float4*)&e2c[jl][h];
        float4 vx = *(const float4*)&v_lds[h];
        float4 d0 = *(const float4*)&d2t[ig * 4 + 0][h];
        float4 d1 = *(const float4*)&d2t[ig * 4 + 1][h];
        float4 d2v = *(const float4*)&d2t[ig * 4 + 2][h];
        float4 d3 = *(const float4*)&d2t[ig * 4 + 3][h];
        a0 = fmaf(tanh_f(ev.x + d0.x), vx.x, a0);
        a0 = fmaf(tanh_f(ev.y + d0.y), vx.y, a0);
        a0 = fmaf(tanh_f(ev.z + d0.z), vx.z, a0);
        a0 = fmaf(tanh_f(ev.w + d0.w), vx.w, a0);
        a1 = fmaf(tanh_f(ev.x + d1.x), vx.x, a1);
        a1 = fmaf(tanh_f(ev.y + d1.y), vx.y, a1);
        a1 = fmaf(tanh_f(ev.z + d1.z), vx.z, a1);
        a1 = fmaf(tanh_f(ev.w + d1.w), vx.w, a1);
        a2 = fmaf(tanh_f(ev.x + d2v.x), vx.x, a2);
        a2 = fmaf(tanh_f(ev.y + d2v.y), vx.y, a2);
        a2 = fmaf(tanh_f(ev.z + d2v.z), vx.z, a2);
        a2 = fmaf(tanh_f(ev.w + d2v.w), vx.w, a2);
        a3 = fmaf(tanh_f(ev.x + d3.x), vx.x, a3);
        a3 = fmaf(tanh_f(ev.y + d3.y), vx.y, a3);
        a3 = fmaf(tanh_f(ev.z + d3.z), vx.z, a3);
        a3 = fmaf(tanh_f(ev.w + d3.w), vx.w, a3);
    }
    float* pr = p_ws + (b * TT + i0 + ig * 4) * TT + j0 + jl;
    pr[0 * TT] = a0;
    pr[1 * TT] = a1;
    pr[2 * TT] = a2;
    pr[3 * TT] = a3;
}

// ---------------------------------------------------------------------------
// Softmax over j with mask (memory-bound finisher).
// grid = 256 = b(32) x 8 row-tiles (16 rows); block = 256 (16 rows x 16 lanes).
// ---------------------------------------------------------------------------
__global__ __launch_bounds__(256) void attn_sm_kernel(
    const float* __restrict__ p_ws, const float* __restrict__ seq,
    float* __restrict__ out) {
    const int blk = blockIdx.x;
    const int b = blk >> 3;
    const int r0 = (blk & 7) * 16;
    const int tid = threadIdx.x;
    const int r = tid >> 4, l16 = tid & 15;
    const int row = (b * TT + r0 + r) * TT;

    float xr[8];
    float m = -1e30f;
#pragma unroll
    for (int k = 0; k < 8; ++k) {
        const int j = l16 + 16 * k;
        float x = p_ws[row + j];
        float sv = (j == 0) ? 0.1f : seq[b * TT + j];
        if (sv == 0.f) x -= 1000.f;
        xr[k] = x;
        m = fmaxf(m, x);
    }
#pragma unroll
    for (int o = 8; o >= 1; o >>= 1) m = fmaxf(m, __shfl_xor(m, o));
    float s = 0.f;
#pragma unroll
    for (int k = 0; k < 8; ++k) {
        xr[k] = __expf(xr[k] - m);
        s += xr[k];
    }
#pragma unroll
    for (int o = 8; o >= 1; o >>= 1) s += __shfl_xor(s, o);
    float inv = rcp_f(s);
#pragma unroll
    for (int k = 0; k < 8; ++k) out[row + l16 + 16 * k] = xr[k] * inv;
}

// ---------------------------------------------------------------------------
extern "C" void kernel_launch(void* const* d_in, const int* in_sizes, int n_in,
                              void* d_out, int out_size, void* d_ws, size_t ws_size,
                              hipStream_t stream) {
    const float* seq = (const float*)d_in[0];
    const int* seq_m = (const int*)d_in[1];
    const float* target = (const float*)d_in[2];
    const float* Wih_e = (const float*)d_in[3];
    const float* Whh_e = (const float*)d_in[4];
    const float* bih_e = (const float*)d_in[5];
    const float* bhh_e = (const float*)d_in[6];
    const float* Wih_d = (const float*)d_in[7];
    const float* Whh_d = (const float*)d_in[8];
    const float* bih_d = (const float*)d_in[9];
    const float* bhh_d = (const float*)d_in[10];
    const float* We = (const float*)d_in[11];
    const float* be = (const float*)d_in[12];
    const float* Wd = (const float*)d_in[13];
    const float* bd = (const float*)d_in[14];
    const float* vv = (const float*)d_in[15];

    float* ws = (float*)d_ws;
    const size_t SZ_ED = (size_t)BB * TT * HH;  // 1,048,576 floats
    float* e2 = ws;
    float* d2 = e2 + SZ_ED;
    float* hs = d2 + SZ_ED;   // [B][2T][H] = 2*SZ_ED floats
    float* p_ws = hs;         // alias: hs dead after proj; attn_p then writes p

    const size_t needed = 4 * SZ_ED * sizeof(float);  // 16 MB
    if (ws_size < needed) return;

    lstm_kernel<<<BB, 1024, 0, stream>>>(seq, seq_m, target, Wih_e, Whh_e, bih_e,
                                         bhh_e, Wih_d, Whh_d, bih_d, bhh_d, hs);
    proj_kernel<<<256, 256, 0, stream>>>(hs, We, be, Wd, bd, e2, d2);
    attn_p_kernel<<<512, 256, 0, stream>>>(e2, d2, vv, p_ws);
    attn_sm_kernel<<<256, 256, 0, stream>>>(p_ws, seq, (float*)d_out);
}